// Round 3
// baseline (1113.956 us; speedup 1.0000x reference)
//
#include <hip/hip_runtime.h>
#include <math.h>

#define B_  64
#define N_  1024
#define H_  64
#define IN_ 512
#define G4  256   // 4*H
#define CH  64    // xg LDS chunk length (steps)

// ---------------------------------------------------------------------------
// Kernel A: xg[b][n][g] = sum_k x[b][n][k] * W_ih[g][k] + b_ih[g] + b_hh[g]
// 128x128 tile, BK=32, 256 threads, 8x8 microtile. (unchanged this round)
// ---------------------------------------------------------------------------
__global__ __launch_bounds__(256) void gemm_xg_kernel(
    const float* __restrict__ x,     // [64][1024][512]
    const float* __restrict__ Wih,   // [256][512]
    const float* __restrict__ bih,
    const float* __restrict__ bhh,
    float* __restrict__ xg)          // [64][1024][256]
{
    __shared__ float As[32][132];    // [k][m_local], +4 pad
    __shared__ float Bs[32][132];    // [k][g_local]

    const int tid = threadIdx.x;
    const int g0  = blockIdx.x * 128;
    const int m0  = blockIdx.y * 128;

    const int tx = tid & 15;
    const int ty = tid >> 4;

    const int r8 = tid >> 3;
    const int kq = tid & 7;

    float acc[8][8];
    #pragma unroll
    for (int i = 0; i < 8; ++i)
        #pragma unroll
        for (int j = 0; j < 8; ++j) acc[i][j] = 0.f;

    for (int k0 = 0; k0 < IN_; k0 += 32) {
        #pragma unroll
        for (int it = 0; it < 4; ++it) {
            const int row = r8 + 32 * it;
            const int m   = m0 + row;
            const int bb  = m & 63;
            const int nn  = m >> 6;
            const float4 v = *(const float4*)&x[((size_t)bb * N_ + nn) * IN_ + k0 + kq * 4];
            As[kq * 4 + 0][row] = v.x;
            As[kq * 4 + 1][row] = v.y;
            As[kq * 4 + 2][row] = v.z;
            As[kq * 4 + 3][row] = v.w;
        }
        #pragma unroll
        for (int it = 0; it < 4; ++it) {
            const int row = r8 + 32 * it;
            const float4 v = *(const float4*)&Wih[(size_t)(g0 + row) * IN_ + k0 + kq * 4];
            Bs[kq * 4 + 0][row] = v.x;
            Bs[kq * 4 + 1][row] = v.y;
            Bs[kq * 4 + 2][row] = v.z;
            Bs[kq * 4 + 3][row] = v.w;
        }
        __syncthreads();

        #pragma unroll
        for (int k = 0; k < 32; ++k) {
            const float4 a0 = *(const float4*)&As[k][ty * 4];
            const float4 a1 = *(const float4*)&As[k][64 + ty * 4];
            const float4 b0 = *(const float4*)&Bs[k][tx * 4];
            const float4 b1 = *(const float4*)&Bs[k][64 + tx * 4];
            const float ar[8] = {a0.x, a0.y, a0.z, a0.w, a1.x, a1.y, a1.z, a1.w};
            const float br[8] = {b0.x, b0.y, b0.z, b0.w, b1.x, b1.y, b1.z, b1.w};
            #pragma unroll
            for (int i = 0; i < 8; ++i)
                #pragma unroll
                for (int j = 0; j < 8; ++j)
                    acc[i][j] = fmaf(ar[i], br[j], acc[i][j]);
        }
        __syncthreads();
    }

    float bias[8];
    #pragma unroll
    for (int j = 0; j < 4; ++j) {
        bias[j]     = bih[g0 + tx * 4 + j]      + bhh[g0 + tx * 4 + j];
        bias[4 + j] = bih[g0 + 64 + tx * 4 + j] + bhh[g0 + 64 + tx * 4 + j];
    }

    #pragma unroll
    for (int i = 0; i < 8; ++i) {
        const int row = (i < 4) ? (ty * 4 + i) : (64 + ty * 4 + i - 4);
        const int m   = m0 + row;
        const size_t base = ((size_t)(m & 63) * N_ + (m >> 6)) * G4;
        float4 o0, o1;
        o0.x = acc[i][0] + bias[0]; o0.y = acc[i][1] + bias[1];
        o0.z = acc[i][2] + bias[2]; o0.w = acc[i][3] + bias[3];
        o1.x = acc[i][4] + bias[4]; o1.y = acc[i][5] + bias[5];
        o1.z = acc[i][6] + bias[6]; o1.w = acc[i][7] + bias[7];
        *(float4*)&xg[base + g0 + tx * 4]      = o0;
        *(float4*)&xg[base + g0 + 64 + tx * 4] = o1;
    }
}

// ---------------------------------------------------------------------------
// Kernel B: recurrent scan v3 — h never touches LDS.
// Every wave keeps the full h vector in a register (lane l = h[l]) and
// broadcasts h[k] via v_readlane -> SGPR into the FMA scalar operand.
// Per step: 64 readlane + 64 FMA (issue-bound, no LDS latency), one
// ds_write_b32 (own gate), ONE barrier, 2 ds_read2_b32 (gather i,f,g,o),
// in-lane c/h update replicated on all 4 waves. xg chunk-staged in LDS via
// global_load_lds, with a one-step register prefetch.
// ---------------------------------------------------------------------------
__device__ __forceinline__ void load_lds_16B(const float* g, float* lds) {
    __builtin_amdgcn_global_load_lds(
        (const __attribute__((address_space(1))) unsigned int*)g,
        (__attribute__((address_space(3))) unsigned int*)lds,
        16, 0, 0);
}

__device__ __forceinline__ float rl(float x, int k) {
    return __uint_as_float(__builtin_amdgcn_readlane(__float_as_uint(x), k));
}

__global__ __launch_bounds__(256) void lstm_scan_kernel(
    const float* __restrict__ xg,    // [B][N][256]
    const float* __restrict__ Whh,   // [256][64]
    float* __restrict__ out)         // [B][N][64]
{
    const int t  = threadIdx.x;
    const int w  = t >> 6;      // wave 0..3 == gate type
    const int l  = t & 63;      // lane == gate element
    const int bb = blockIdx.x;

    __shared__ float xg_sh[2][CH][G4];   // 128 KiB
    __shared__ float gate_sh[2][4][64];  // [buf][gate_type][elem]

    // W_hh row t -> 64 VGPRs
    float4 w4[16];
    #pragma unroll
    for (int q = 0; q < 16; ++q)
        w4[q] = *(const float4*)&Whh[(size_t)t * H_ + q * 4];

    const float* xg_b = xg + (size_t)bb * N_ * G4;

    // prologue: stage chunk 0 into buf 0 (wave w loads rows w, w+4, ...)
    #pragma unroll
    for (int jj = 0; jj < CH / 4; ++jj) {
        const int j = w + 4 * jj;
        load_lds_16B(xg_b + (size_t)j * G4 + l * 4, &xg_sh[0][j][0]);
    }
    float c = 0.f;
    float h = 0.f;              // lane l holds h[l], replicated in every wave
    __syncthreads();            // drains vmcnt -> chunk 0 ready

    float xgr = xg_sh[0][0][t]; // xg for step 0

    int gbuf = 0;
    for (int n = 0; n < N_; ++n) {
        const int s    = n & (CH - 1);
        const int cbuf = (n >> 6) & 1;

        // stage chunk n+CH (drained at this step's barrier)
        if (s == 0 && n + CH < N_) {
            #pragma unroll
            for (int jj = 0; jj < CH / 4; ++jj) {
                const int j = w + 4 * jj;
                load_lds_16B(xg_b + (size_t)(n + CH + j) * G4 + l * 4,
                             &xg_sh[cbuf ^ 1][j][0]);
            }
        }

        // prefetch next step's xg from LDS (latency hides under readlanes)
        const int n1 = (n + 1 < N_) ? (n + 1) : (N_ - 1);
        const float xg_next = xg_sh[(n1 >> 6) & 1][n1 & (CH - 1)][t];

        // ---- phase 1: gates = xg + W_hh[t] . h via readlane broadcast ----
        float a0 = xgr, a1 = 0.f, a2 = 0.f, a3 = 0.f;
        #pragma unroll
        for (int q = 0; q < 4; ++q) {
            const float4 wA = w4[q * 4 + 0];
            const float4 wB = w4[q * 4 + 1];
            const float4 wC = w4[q * 4 + 2];
            const float4 wD = w4[q * 4 + 3];
            const int k = q * 16;
            a0 = fmaf(wA.x, rl(h, k + 0),  a0);
            a0 = fmaf(wA.y, rl(h, k + 1),  a0);
            a0 = fmaf(wA.z, rl(h, k + 2),  a0);
            a0 = fmaf(wA.w, rl(h, k + 3),  a0);
            a1 = fmaf(wB.x, rl(h, k + 4),  a1);
            a1 = fmaf(wB.y, rl(h, k + 5),  a1);
            a1 = fmaf(wB.z, rl(h, k + 6),  a1);
            a1 = fmaf(wB.w, rl(h, k + 7),  a1);
            a2 = fmaf(wC.x, rl(h, k + 8),  a2);
            a2 = fmaf(wC.y, rl(h, k + 9),  a2);
            a2 = fmaf(wC.z, rl(h, k + 10), a2);
            a2 = fmaf(wC.w, rl(h, k + 11), a2);
            a3 = fmaf(wD.x, rl(h, k + 12), a3);
            a3 = fmaf(wD.y, rl(h, k + 13), a3);
            a3 = fmaf(wD.z, rl(h, k + 14), a3);
            a3 = fmaf(wD.w, rl(h, k + 15), a3);
        }
        const float accv = (a0 + a1) + (a2 + a3);

        // activation: wave 2 = tanh, others sigmoid (wave-uniform branch)
        float v;
        if (w == 2) {
            v = 1.f - 2.f * __builtin_amdgcn_rcpf(1.f + __expf(2.f * accv));
        } else {
            v = __builtin_amdgcn_rcpf(1.f + __expf(-accv));
        }
        gate_sh[gbuf][w][l] = v;    // conflict-free b32 write
        __syncthreads();            // the ONLY barrier per step

        // ---- phase 2: c/h update, in-lane, replicated on every wave ----
        const float gi = gate_sh[gbuf][0][l];
        const float gf = gate_sh[gbuf][1][l];
        const float gg = gate_sh[gbuf][2][l];
        const float go = gate_sh[gbuf][3][l];
        c = fmaf(gf, c, gi * gg);
        const float th = 1.f - 2.f * __builtin_amdgcn_rcpf(1.f + __expf(2.f * c));
        h = go * th;
        if ((n & 3) == w)           // rotate store duty across waves
            out[((size_t)bb * N_ + n) * H_ + l] = h;

        xgr  = xg_next;
        gbuf ^= 1;
    }
}

extern "C" void kernel_launch(void* const* d_in, const int* in_sizes, int n_in,
                              void* d_out, int out_size, void* d_ws, size_t ws_size,
                              hipStream_t stream)
{
    const float* x   = (const float*)d_in[0];
    const float* Wih = (const float*)d_in[1];
    const float* Whh = (const float*)d_in[2];
    const float* bih = (const float*)d_in[3];
    const float* bhh = (const float*)d_in[4];
    float* out = (float*)d_out;
    float* xg  = (float*)d_ws;   // 64 MiB scratch, layout [B][N][256]

    dim3 ggrid(2, 512);
    gemm_xg_kernel<<<ggrid, 256, 0, stream>>>(x, Wih, bih, bhh, xg);
    lstm_scan_kernel<<<64, 256, 0, stream>>>(xg, Whh, out);
}

// Round 4
// 1026.814 us; speedup vs baseline: 1.0849x; 1.0849x over previous
//
#include <hip/hip_runtime.h>
#include <math.h>

#define B_  64
#define N_  1024
#define H_  64
#define IN_ 512
#define G4  256   // 4*H
#define CH  64    // xg LDS chunk length (steps)

// ---------------------------------------------------------------------------
// Kernel A: xg[b][n][g] = sum_k x[b][n][k] * W_ih[g][k] + b_ih[g] + b_hh[g]
// 128x128 tile, BK=32, 256 threads, 8x8 microtile. (unchanged this round)
// ---------------------------------------------------------------------------
__global__ __launch_bounds__(256) void gemm_xg_kernel(
    const float* __restrict__ x,     // [64][1024][512]
    const float* __restrict__ Wih,   // [256][512]
    const float* __restrict__ bih,
    const float* __restrict__ bhh,
    float* __restrict__ xg)          // [64][1024][256]
{
    __shared__ float As[32][132];    // [k][m_local], +4 pad
    __shared__ float Bs[32][132];    // [k][g_local]

    const int tid = threadIdx.x;
    const int g0  = blockIdx.x * 128;
    const int m0  = blockIdx.y * 128;

    const int tx = tid & 15;
    const int ty = tid >> 4;

    const int r8 = tid >> 3;
    const int kq = tid & 7;

    float acc[8][8];
    #pragma unroll
    for (int i = 0; i < 8; ++i)
        #pragma unroll
        for (int j = 0; j < 8; ++j) acc[i][j] = 0.f;

    for (int k0 = 0; k0 < IN_; k0 += 32) {
        #pragma unroll
        for (int it = 0; it < 4; ++it) {
            const int row = r8 + 32 * it;
            const int m   = m0 + row;
            const int bb  = m & 63;
            const int nn  = m >> 6;
            const float4 v = *(const float4*)&x[((size_t)bb * N_ + nn) * IN_ + k0 + kq * 4];
            As[kq * 4 + 0][row] = v.x;
            As[kq * 4 + 1][row] = v.y;
            As[kq * 4 + 2][row] = v.z;
            As[kq * 4 + 3][row] = v.w;
        }
        #pragma unroll
        for (int it = 0; it < 4; ++it) {
            const int row = r8 + 32 * it;
            const float4 v = *(const float4*)&Wih[(size_t)(g0 + row) * IN_ + k0 + kq * 4];
            Bs[kq * 4 + 0][row] = v.x;
            Bs[kq * 4 + 1][row] = v.y;
            Bs[kq * 4 + 2][row] = v.z;
            Bs[kq * 4 + 3][row] = v.w;
        }
        __syncthreads();

        #pragma unroll
        for (int k = 0; k < 32; ++k) {
            const float4 a0 = *(const float4*)&As[k][ty * 4];
            const float4 a1 = *(const float4*)&As[k][64 + ty * 4];
            const float4 b0 = *(const float4*)&Bs[k][tx * 4];
            const float4 b1 = *(const float4*)&Bs[k][64 + tx * 4];
            const float ar[8] = {a0.x, a0.y, a0.z, a0.w, a1.x, a1.y, a1.z, a1.w};
            const float br[8] = {b0.x, b0.y, b0.z, b0.w, b1.x, b1.y, b1.z, b1.w};
            #pragma unroll
            for (int i = 0; i < 8; ++i)
                #pragma unroll
                for (int j = 0; j < 8; ++j)
                    acc[i][j] = fmaf(ar[i], br[j], acc[i][j]);
        }
        __syncthreads();
    }

    float bias[8];
    #pragma unroll
    for (int j = 0; j < 4; ++j) {
        bias[j]     = bih[g0 + tx * 4 + j]      + bhh[g0 + tx * 4 + j];
        bias[4 + j] = bih[g0 + 64 + tx * 4 + j] + bhh[g0 + 64 + tx * 4 + j];
    }

    #pragma unroll
    for (int i = 0; i < 8; ++i) {
        const int row = (i < 4) ? (ty * 4 + i) : (64 + ty * 4 + i - 4);
        const int m   = m0 + row;
        const size_t base = ((size_t)(m & 63) * N_ + (m >> 6)) * G4;
        float4 o0, o1;
        o0.x = acc[i][0] + bias[0]; o0.y = acc[i][1] + bias[1];
        o0.z = acc[i][2] + bias[2]; o0.w = acc[i][3] + bias[3];
        o1.x = acc[i][4] + bias[4]; o1.y = acc[i][5] + bias[5];
        o1.z = acc[i][6] + bias[6]; o1.w = acc[i][7] + bias[7];
        *(float4*)&xg[base + g0 + tx * 4]      = o0;
        *(float4*)&xg[base + g0 + 64 + tx * 4] = o1;
    }
}

// ---------------------------------------------------------------------------
// Kernel B: recurrent scan v4 — NO global memory ops in the steady loop.
// Rationale: __syncthreads drains vmcnt(0); any in-loop global store/load
// puts a ~300-600 cyc L2 round-trip on EVERY step's barrier. All out-stores
// are batched per 64-step chunk, sharing the once-per-chunk vmcnt drain with
// the global_load_lds xg staging.
//  - hist_sh[s][l]: h history, written by ALL waves each step (identical
//    values) => own-wave visibility; doubles as the h broadcast source for
//    the next step's matvec (uniform-address b128 reads, conflict-free).
//  - gates: double-buffered, ONE barrier per step.
// ---------------------------------------------------------------------------
__device__ __forceinline__ void load_lds_16B(const float* g, float* lds) {
    __builtin_amdgcn_global_load_lds(
        (const __attribute__((address_space(1))) unsigned int*)g,
        (__attribute__((address_space(3))) unsigned int*)lds,
        16, 0, 0);
}

__global__ __launch_bounds__(256) void lstm_scan_kernel(
    const float* __restrict__ xg,    // [B][N][256]
    const float* __restrict__ Whh,   // [256][64]
    float* __restrict__ out)         // [B][N][64]
{
    const int t  = threadIdx.x;
    const int w  = t >> 6;      // wave 0..3 == gate type
    const int l  = t & 63;      // lane == gate element
    const int bb = blockIdx.x;

    __shared__ float xg_sh[2][CH][G4];   // 128 KiB
    __shared__ float gate_sh[2][4][64];  // [buf][gate_type][elem]
    __shared__ float hist_sh[CH][64];    // 16 KiB h history (+ h broadcast)

    // W_hh row t -> 64 VGPRs
    float4 w4[16];
    #pragma unroll
    for (int q = 0; q < 16; ++q)
        w4[q] = *(const float4*)&Whh[(size_t)t * H_ + q * 4];

    const float* xg_b = xg + (size_t)bb * N_ * G4;

    // prologue: stage chunk 0 into buf 0 (wave w loads rows w, w+4, ...)
    #pragma unroll
    for (int jj = 0; jj < CH / 4; ++jj) {
        const int j = w + 4 * jj;
        load_lds_16B(xg_b + (size_t)j * G4 + l * 4, &xg_sh[0][j][0]);
    }
    hist_sh[CH - 1][l] = 0.f;   // h(-1) = 0; (n-1)&63 == 63 at n=0
    float c = 0.f;
    __syncthreads();            // drains vmcnt -> chunk 0 ready

    float xgr = xg_sh[0][0][t]; // xg for step 0

    int gbuf = 0;
    for (int n = 0; n < N_; ++n) {
        const int s    = n & (CH - 1);
        const int cbuf = (n >> 6) & 1;

        if (s == 0) {
            // dump previous chunk's h history -> out (coalesced dwordx4).
            // Stores drain at THIS step's barrier: once per 64 steps.
            if (n > 0) {
                const int prev0 = n - CH;
                #pragma unroll
                for (int r = 0; r < 4; ++r) {
                    const int row = r * 16 + (t >> 4);
                    const int col = (t & 15) * 4;
                    const float4 hv = *(const float4*)&hist_sh[row][col];
                    *(float4*)&out[((size_t)bb * N_ + prev0 + row) * H_ + col] = hv;
                }
            }
            // stage chunk n+CH (drained at this step's barrier too)
            if (n + CH < N_) {
                #pragma unroll
                for (int jj = 0; jj < CH / 4; ++jj) {
                    const int j = w + 4 * jj;
                    load_lds_16B(xg_b + (size_t)(n + CH + j) * G4 + l * 4,
                                 &xg_sh[cbuf ^ 1][j][0]);
                }
            }
        }

        // prefetch next step's xg from LDS (hides under the h-read stream)
        const int n1 = (n + 1 < N_) ? (n + 1) : (N_ - 1);
        const float xg_next = xg_sh[(n1 >> 6) & 1][n1 & (CH - 1)][t];

        // ---- phase 1: gates = xg + W_hh[t] . h  (h = hist_sh[(n-1)&63]) ----
        const float* hp = &hist_sh[(n - 1) & (CH - 1)][0];
        float a0 = xgr, a1 = 0.f, a2 = 0.f, a3 = 0.f;
        #pragma unroll
        for (int q = 0; q < 4; ++q) {
            const float4 h0 = *(const float4*)&hp[q * 16 + 0];   // broadcast
            const float4 h1 = *(const float4*)&hp[q * 16 + 4];
            const float4 h2 = *(const float4*)&hp[q * 16 + 8];
            const float4 h3 = *(const float4*)&hp[q * 16 + 12];
            const float4 wa = w4[q * 4 + 0];
            const float4 wb = w4[q * 4 + 1];
            const float4 wc = w4[q * 4 + 2];
            const float4 wd = w4[q * 4 + 3];
            a0 = fmaf(wa.x, h0.x, a0); a0 = fmaf(wa.y, h0.y, a0);
            a0 = fmaf(wa.z, h0.z, a0); a0 = fmaf(wa.w, h0.w, a0);
            a1 = fmaf(wb.x, h1.x, a1); a1 = fmaf(wb.y, h1.y, a1);
            a1 = fmaf(wb.z, h1.z, a1); a1 = fmaf(wb.w, h1.w, a1);
            a2 = fmaf(wc.x, h2.x, a2); a2 = fmaf(wc.y, h2.y, a2);
            a2 = fmaf(wc.z, h2.z, a2); a2 = fmaf(wc.w, h2.w, a2);
            a3 = fmaf(wd.x, h3.x, a3); a3 = fmaf(wd.y, h3.y, a3);
            a3 = fmaf(wd.z, h3.z, a3); a3 = fmaf(wd.w, h3.w, a3);
        }
        const float accv = (a0 + a1) + (a2 + a3);

        // activation: wave 2 = tanh, others sigmoid (wave-uniform branch)
        float v;
        if (w == 2) {
            v = 1.f - 2.f * __builtin_amdgcn_rcpf(1.f + __expf(2.f * accv));
        } else {
            v = __builtin_amdgcn_rcpf(1.f + __expf(-accv));
        }
        gate_sh[gbuf][w][l] = v;    // conflict-free b32 write
        __syncthreads();            // the ONLY barrier per step

        // ---- phase 2: c/h update, in-lane, replicated on every wave ----
        const float gi = gate_sh[gbuf][0][l];
        const float gf = gate_sh[gbuf][1][l];
        const float gg = gate_sh[gbuf][2][l];
        const float go = gate_sh[gbuf][3][l];
        c = fmaf(gf, c, gi * gg);
        const float th = 1.f - 2.f * __builtin_amdgcn_rcpf(1.f + __expf(2.f * c));
        const float h  = go * th;
        hist_sh[s][l] = h;          // all waves write identical values

        xgr  = xg_next;
        gbuf ^= 1;
    }

    // epilogue: dump the final chunk's history (steps N-64 .. N-1)
    #pragma unroll
    for (int r = 0; r < 4; ++r) {
        const int row = r * 16 + (t >> 4);
        const int col = (t & 15) * 4;
        const float4 hv = *(const float4*)&hist_sh[row][col];
        *(float4*)&out[((size_t)bb * N_ + (N_ - CH) + row) * H_ + col] = hv;
    }
}

extern "C" void kernel_launch(void* const* d_in, const int* in_sizes, int n_in,
                              void* d_out, int out_size, void* d_ws, size_t ws_size,
                              hipStream_t stream)
{
    const float* x   = (const float*)d_in[0];
    const float* Wih = (const float*)d_in[1];
    const float* Whh = (const float*)d_in[2];
    const float* bih = (const float*)d_in[3];
    const float* bhh = (const float*)d_in[4];
    float* out = (float*)d_out;
    float* xg  = (float*)d_ws;   // 64 MiB scratch, layout [B][N][256]

    dim3 ggrid(2, 512);
    gemm_xg_kernel<<<ggrid, 256, 0, stream>>>(x, Wih, bih, bhh, xg);
    lstm_scan_kernel<<<64, 256, 0, stream>>>(xg, Whh, out);
}